// Round 6
// baseline (241.753 us; speedup 1.0000x reference)
//
#include <hip/hip_runtime.h>
#include <math.h>

#define TLEN 613376
#define OLEN 617472          // 4096 + 1024*599
#define NFR  600             // total frames
#define NB   2049            // bins
#define PI_F  3.14159265358979323846f
#define PI2_F 6.28318530717958647693f
#define PHYS(i) ((i) + ((i) >> 4))   // LDS pad

// periodic hann window
__device__ __forceinline__ float winf(int j) {
  return 0.5f - 0.5f * __cosf(1.5339807878856412e-3f * (float)j);  // 2*pi/4096
}

__device__ __forceinline__ float wsum_at(int m) {   // OLA window-power sum (edge-aware)
  int f_max = m >> 10; if (f_max > 599) f_max = 599;
  int f_min = (m - 3072) >> 10; if (f_min < 0) f_min = 0;
  float ws = 0.f;
  for (int f2 = f_min; f2 <= f_max; ++f2) {
    float w = winf(m - (f2 << 10));
    ws += w * w;
  }
  return (ws > 1e-11f) ? ws : 1.0f;
}

__device__ __forceinline__ float reflect_load(const float* __restrict__ x, int pos) {
  int k = pos - 2048;
  if (k < 0) k = -k;
  else if (k >= TLEN) k = 2 * TLEN - 2 - k;
  return x[k];
}

__device__ __forceinline__ float2 cmul(float2 a, float2 b) {
  return make_float2(a.x * b.x - a.y * b.y, a.x * b.y + a.y * b.x);
}
__device__ __forceinline__ float2 cadd(float2 a, float2 b) { return make_float2(a.x + b.x, a.y + b.y); }
__device__ __forceinline__ float2 csub(float2 a, float2 b) { return make_float2(a.x - b.x, a.y - b.y); }
template<int SGN>
__device__ __forceinline__ float2 muli(float2 a) {   // multiply by SGN*i
  return (SGN > 0) ? make_float2(-a.y, a.x) : make_float2(a.y, -a.x);
}

template<int SGN>
__device__ __forceinline__ void fft4(float2 v[4]) {
  float2 t0 = cadd(v[0], v[2]), t1 = csub(v[0], v[2]);
  float2 t2 = cadd(v[1], v[3]), t3 = csub(v[1], v[3]);
  float2 it3 = muli<SGN>(t3);
  v[0] = cadd(t0, t2); v[2] = csub(t0, t2);
  v[1] = cadd(t1, it3); v[3] = csub(t1, it3);
}

template<int SGN>
__device__ __forceinline__ void fft8(float2 v[8]) {
  const float C = 0.70710678118654752440f;
  const float s = (SGN > 0) ? 1.0f : -1.0f;
  float2 t0 = cadd(v[0], v[4]), t1 = csub(v[0], v[4]);
  float2 t2 = cadd(v[2], v[6]), t3 = csub(v[2], v[6]);
  float2 e0 = cadd(t0, t2), e2 = csub(t0, t2);
  float2 it3 = muli<SGN>(t3);
  float2 e1 = cadd(t1, it3), e3 = csub(t1, it3);
  t0 = cadd(v[1], v[5]); t1 = csub(v[1], v[5]);
  t2 = cadd(v[3], v[7]); t3 = csub(v[3], v[7]);
  float2 o0 = cadd(t0, t2), o2 = csub(t0, t2);
  it3 = muli<SGN>(t3);
  float2 o1 = cadd(t1, it3), o3 = csub(t1, it3);
  float2 o1w = make_float2(C * (o1.x - s * o1.y), C * (o1.y + s * o1.x));
  float2 o2w = muli<SGN>(o2);
  float2 o3w = make_float2(C * (-o3.x - s * o3.y), C * (-o3.y + s * o3.x));
  v[0] = cadd(e0, o0);  v[4] = csub(e0, o0);
  v[1] = cadd(e1, o1w); v[5] = csub(e1, o1w);
  v[2] = cadd(e2, o2w); v[6] = csub(e2, o2w);
  v[3] = cadd(e3, o3w); v[7] = csub(e3, o3w);
}

template<int SGN>
__device__ __forceinline__ void twiddle8(float2 v[8], float ang) {
  float sn, cs;
  __sincosf((SGN > 0) ? ang : -ang, &sn, &cs);
  float2 w1 = make_float2(cs, sn);
  float2 w = w1;
  v[1] = cmul(v[1], w);
#pragma unroll
  for (int r = 2; r < 8; ++r) { w = cmul(w, w1); v[r] = cmul(v[r], w); }
}

// Stockham stages 1-3 (radix-8); stage-3 result left in LDS.
template<int SGN>
__device__ __forceinline__ void fft2048_mid(float2* lds, float2 v[8], int tid) {
  fft8<SGN>(v);
#pragma unroll
  for (int r = 0; r < 8; ++r) { int i = tid * 8 + r; lds[PHYS(i)] = v[r]; }
  __syncthreads();
#pragma unroll
  for (int r = 0; r < 8; ++r) v[r] = lds[PHYS(tid + 256 * r)];
  twiddle8<SGN>(v, PI2_F * (1.0f / 64.0f) * (float)(tid & 7));      // Ns=8
  fft8<SGN>(v);
  __syncthreads();
#pragma unroll
  for (int r = 0; r < 8; ++r) { int i = ((tid >> 3) << 6) + (tid & 7) + 8 * r; lds[PHYS(i)] = v[r]; }
  __syncthreads();
#pragma unroll
  for (int r = 0; r < 8; ++r) v[r] = lds[PHYS(tid + 256 * r)];
  twiddle8<SGN>(v, PI2_F * (1.0f / 512.0f) * (float)(tid & 63));    // Ns=64
  fft8<SGN>(v);
  __syncthreads();
#pragma unroll
  for (int r = 0; r < 8; ++r) { int i = ((tid >> 6) << 9) + (tid & 63) + 64 * r; lds[PHYS(i)] = v[r]; }
  __syncthreads();
}

// final radix-4 stage (Ns=512): butterfly jj in [0,512); outputs z[jj + 512 k] = u[k]
template<int SGN>
__device__ __forceinline__ void fft2048_last(const float2* lds, int jj, float2 u[4]) {
#pragma unroll
  for (int r = 0; r < 4; ++r) u[r] = lds[PHYS(jj + 512 * r)];
  float sn, cs;
  float ang = PI2_F * (1.0f / 2048.0f) * (float)jj;
  __sincosf((SGN > 0) ? ang : -ang, &sn, &cs);
  float2 w1 = make_float2(cs, sn);
  float2 w2 = cmul(w1, w1);
  float2 w3 = cmul(w2, w1);
  u[1] = cmul(u[1], w1); u[2] = cmul(u[2], w2); u[3] = cmul(u[3], w3);
  fft4<SGN>(u);
}

// ---------------- forward STFT: one block per (n,c,f) frame ----------------
__global__ __launch_bounds__(256, 6) void stft_kernel(const float* __restrict__ audio,
                                                      float2* __restrict__ X) {
  __shared__ float2 lds[2176];
  int bid = blockIdx.x;             // nc*600 + f
  int f  = bid % NFR;
  int nc = bid / NFR;
  const float* x = audio + (size_t)nc * TLEN;
  int tid = threadIdx.x;
  int base = f * 1024;
  float2 v[8];
#pragma unroll
  for (int r = 0; r < 8; ++r) {
    int k = tid + 256 * r;
    int j0 = 2 * k;
    v[r] = make_float2(reflect_load(x, base + j0)     * winf(j0),
                       reflect_load(x, base + j0 + 1) * winf(j0 + 1));
  }
  fft2048_mid<-1>(lds, v, tid);
  fft2048_last<-1>(lds, tid,        v);
  fft2048_last<-1>(lds, tid + 256,  v + 4);
  __syncthreads();
#pragma unroll
  for (int r = 0; r < 4; ++r) lds[PHYS(tid + 512 * r)] = v[r];
#pragma unroll
  for (int r = 0; r < 4; ++r) lds[PHYS(tid + 256 + 512 * r)] = v[4 + r];
  __syncthreads();
  float2* out = X + (size_t)bid * NB;
  float sn0, cs0;
  __sincosf(-PI_F * (float)tid * (1.0f / 2048.0f), &sn0, &cs0);
  float2 ph = make_float2(cs0, sn0);
  const float2 rot = make_float2(0.92387953251128675613f, -0.38268343236508977173f);
#pragma unroll
  for (int r = 0; r < 9; ++r) {
    int k = tid + 256 * r;
    if (k <= 2048) {
      float2 Zk = lds[PHYS(k & 2047)];
      float2 Zm = lds[PHYS((2048 - k) & 2047)];
      float Ex = 0.5f * (Zk.x + Zm.x), Ey = 0.5f * (Zk.y - Zm.y);
      float Dx = 0.5f * (Zk.x - Zm.x), Dy = 0.5f * (Zk.y + Zm.y);
      float Ox = Dy, Oy = -Dx;                       // O = -i*D
      out[k] = make_float2(Ex + Ox * ph.x - Oy * ph.y, Ey + Ox * ph.y + Oy * ph.x);
    }
    ph = cmul(ph, rot);
  }
}

// ------- per-(n,chunk,b) covariance stats (float4/bin) + fused chunk max -------
__global__ __launch_bounds__(256) void stats_kernel(const float2* __restrict__ X,
                                                    float* __restrict__ stats4,
                                                    unsigned int* __restrict__ maxsq) {
  __shared__ unsigned int sm;
  if (threadIdx.x == 0) sm = 0u;
  __syncthreads();
  int b = blockIdx.x * 256 + threadIdx.x;
  bool ok = (b < NB);
  int g = blockIdx.y;                 // n*2 + chunk
  int n = g >> 1, chunk = g & 1;
  int t0 = blockIdx.z * 75;
  const float2* X0 = X + ((size_t)(n * 2 + 0) * NFR + chunk * 300 + t0) * NB + (ok ? b : 0);
  const float2* X1 = X + ((size_t)(n * 2 + 1) * NFR + chunk * 300 + t0) * NB + (ok ? b : 0);
  float s00 = 0.f, s11 = 0.f, sre = 0.f, sim = 0.f, lmax = 0.f;
  if (ok) {
    for (int t = 0; t < 75; ++t) {
      float2 a = X0[(size_t)t * NB];
      float2 c = X1[(size_t)t * NB];
      float pa = a.x * a.x + a.y * a.y;
      float pc = c.x * c.x + c.y * c.y;
      s00 += pa; s11 += pc;
      sre += a.x * c.x + a.y * c.y;
      sim += a.y * c.x - a.x * c.y;
      lmax = fmaxf(lmax, fmaxf(pa, pc));
    }
  }
  atomicMax(&sm, __float_as_uint(lmax));
  __syncthreads();
  if (threadIdx.x == 0) atomicMax(&maxsq[g], sm);
  if (ok) {
    float* sp = stats4 + ((size_t)g * NB + b) * 4;
    unsafeAtomicAdd(sp + 0, s00);
    unsafeAtomicAdd(sp + 1, s11);
    unsafeAtomicAdd(sp + 2, sre);
    unsafeAtomicAdd(sp + 3, sim);
  }
}

// ---------------- alpha_s + K = sum_s alpha per (g,b) ----------------
__global__ __launch_bounds__(256) void alpha_kernel(const float* __restrict__ Wmask,
                                                    const float4* __restrict__ stats4,
                                                    const unsigned int* __restrict__ maxsq,
                                                    float* __restrict__ alpha,
                                                    float* __restrict__ Ksum) {
  int idx = blockIdx.x * 256 + threadIdx.x;
  if (idx >= 4 * NB) return;
  int b = idx % NB;
  int g = idx / NB;
  float ma2 = fmaxf(1.0f, __uint_as_float(maxsq[g]) * 0.01f);   // max_abs^2
  float4 s4 = stats4[(size_t)g * NB + b];
  float P = 0.5f * (s4.x + s4.y) / ma2;
  float K = 0.f;
#pragma unroll
  for (int s = 0; s < 4; ++s) {
    float mv = 1.0f / (1.0f + expf(-Wmask[s * NB + b]));
    float m2 = mv * mv;
    float a = (m2 * m2) / (1e-10f + m2 * P);
    alpha[(size_t)(g * 4 + s) * NB + b] = a;
    K += a;
  }
  Ksum[(size_t)g * NB + b] = K;
}

// ------- Wiener core (s-independent field): Wc[t,c] = p̂ * (G * inv(Cxx) * x)[c] -------
__global__ __launch_bounds__(256) void wiener_kernel(const float2* __restrict__ X,
                                                     const float4* __restrict__ stats4,
                                                     const float* __restrict__ Ksum,
                                                     const unsigned int* __restrict__ maxsq,
                                                     float2* __restrict__ Wc) {
  int idx = blockIdx.x * 256 + threadIdx.x;
  if (idx >= 4 * 300 * NB) return;
  int b = idx % NB;
  int gt = idx / NB;
  int t = gt % 300;
  int g = gt / 300;
  int n = g >> 1, chunk = g & 1;
  int f = chunk * 300 + t;
  float ima2 = 1.0f / fmaxf(1.0f, __uint_as_float(maxsq[g]) * 0.01f);
  float4 s4 = stats4[(size_t)g * NB + b];
  float g00 = s4.x * ima2, g11 = s4.y * ima2, gre = s4.z * ima2, gim = s4.w * ima2;
  float K = Ksum[(size_t)g * NB + b];
  float2 x0 = X[((size_t)(n * 2 + 0) * NFR + f) * NB + b];
  float2 x1 = X[((size_t)(n * 2 + 1) * NFR + f) * NB + b];
  float ph = 0.5f * ((x0.x * x0.x + x0.y * x0.y) + (x1.x * x1.x + x1.y * x1.y)) * ima2;
  float pk = ph * K;
  float M00 = 1e-5f + pk * g00;
  float M11 = 1e-5f + pk * g11;
  float Mre = pk * gre, Mim = pk * gim;                // M01
  float det = M00 * M11 - (Mre * Mre + Mim * Mim);
  float sc = ph / det;
  float u0x = M11 * x0.x - (Mre * x1.x - Mim * x1.y);
  float u0y = M11 * x0.y - (Mre * x1.y + Mim * x1.x);
  float u1x = M00 * x1.x - (Mre * x0.x + Mim * x0.y);
  float u1y = M00 * x1.y - (Mre * x0.y - Mim * x0.x);
  float w0x = g00 * u0x + (gre * u1x - gim * u1y);
  float w0y = g00 * u0y + (gre * u1y + gim * u1x);
  float w1x = (gre * u0x + gim * u0y) + g11 * u1x;
  float w1y = (gre * u0y - gim * u0x) + g11 * u1y;
  float2* out = Wc + ((size_t)(n * NFR + f) * 2) * NB + b;
  out[0]  = make_float2(w0x * sc, w0y * sc);
  out[NB] = make_float2(w1x * sc, w1y * sc);
}

// ---- inverse rFFT per frame + NON-ATOMIC OLA; MODE: 0=store, 1=add, 2=add+finalize ----
template<int MODE>
__global__ __launch_bounds__(256, 8) void istft_pass_kernel(const float2* __restrict__ Wc,
                                                            const float* __restrict__ alpha,
                                                            float* __restrict__ accum,
                                                            float* __restrict__ out,
                                                            int pass) {
  __shared__ float2 lds[2176];
  int bid = blockIdx.x;                  // plane*150 + fi, plane = ((n*4+s)*2+c)
  int fi = bid % 150;
  int plane = bid / 150;
  int c = plane & 1;
  int s = (plane >> 1) & 3;
  int n = plane >> 3;
  int f = 4 * fi + pass;
  int g = n * 2 + (f >= 300 ? 1 : 0);
  int tid = threadIdx.x;
  const float2* Wrow = Wc + ((size_t)(n * NFR + f) * 2 + c) * NB;
  const float*  arow = alpha + (size_t)(g * 4 + s) * NB;
  float* acc = accum + (size_t)plane * OLEN + (size_t)f * 1024;

  // Prefetch the OLA read-modify-write inputs before the FFT: addresses are
  // known at entry, and this hides the global read latency behind ~8 us of
  // FFT compute instead of serializing it after the final barrier.
  float2 pre[8];
  if (MODE >= 1) {
#pragma unroll
    for (int half = 0; half < 2; ++half) {
#pragma unroll
      for (int r = 0; r < 4; ++r) {
        int m = tid + 256 * half + 512 * r;
        pre[half * 4 + r] = *(const float2*)&acc[2 * m];
      }
    }
  }

  float2 v[8];
  float sn0, cs0;
  __sincosf(PI_F * (float)tid * (1.0f / 2048.0f), &sn0, &cs0);
  float2 ph = make_float2(cs0, sn0);
  const float2 rot = make_float2(0.92387953251128675613f, 0.38268343236508977173f);
#pragma unroll
  for (int r = 0; r < 8; ++r) {
    int k = tid + 256 * r;
    float ak = arow[k];
    float2 sk = Wrow[k]; sk.x *= ak; sk.y *= ak;
    int rk = 2048 - k;
    float am = arow[rk];
    float2 sv = Wrow[rk]; sv.x *= am; sv.y *= am;
    float Ex = 0.5f * (sk.x + sv.x), Ey = 0.5f * (sk.y - sv.y);
    float Dx = 0.5f * (sk.x - sv.x), Dy = 0.5f * (sk.y + sv.y);
    float Ox = Dx * ph.x - Dy * ph.y, Oy = Dx * ph.y + Dy * ph.x;  // O = D*e^{+i pi k/2048}
    v[r] = make_float2(Ex - Oy, Ey + Ox);                           // Z = E + iO
    ph = cmul(ph, rot);
  }
  fft2048_mid<1>(lds, v, tid);
  float* outp = out + (size_t)plane * TLEN;
  const float scale = 1.0f / 2048.0f;
#pragma unroll
  for (int half = 0; half < 2; ++half) {
    int jj = tid + 256 * half;
    float2 u[4];
    fft2048_last<1>(lds, jj, u);
#pragma unroll
    for (int r = 0; r < 4; ++r) {
      int m = jj + 512 * r;
      int j0 = 2 * m;
      float2 val = make_float2(u[r].x * scale * winf(j0),
                               u[r].y * scale * winf(j0 + 1));
      float2* p = (float2*)&acc[j0];
      if (MODE == 0) {
        *p = val;
      } else if (MODE == 1) {
        float2 o = pre[half * 4 + r];
        val.x += o.x; val.y += o.y;
        *p = val;
      } else {
        int gm = f * 1024 + j0;                       // accum coordinate (even)
        if (gm < 615424) {                            // out covers [2048, 615424)
          float2 o = pre[half * 4 + r];
          val.x += o.x; val.y += o.y;
          float i0, i1;
          if (gm >= 3072 && gm + 1 < 614400) {        // interior: wsum == 1.5
            i0 = 0.66666666666666667f; i1 = i0;
          } else {
            i0 = 1.0f / wsum_at(gm); i1 = 1.0f / wsum_at(gm + 1);
          }
          float2* po = (float2*)&outp[gm - 2048];
          *po = make_float2(val.x * i0, val.y * i1);
        }
      }
    }
  }
  if (MODE == 0 && fi == 149) {
    // zero the plane tail [614400, OLEN) not covered by class-0 frames
    float* tail = accum + (size_t)plane * OLEN + 614400;
    for (int i = tid; i < OLEN - 614400; i += 256) tail[i] = 0.f;
  }
  if (MODE == 2 && fi == 0) {
    // finalize head samples m in [2048, 3072): complete after pass 2
    float* accp = accum + (size_t)plane * OLEN;
    for (int m = 2048 + tid; m < 3072; m += 256) {
      outp[m - 2048] = accp[m] / wsum_at(m);
    }
  }
}

extern "C" void kernel_launch(void* const* d_in, const int* in_sizes, int n_in,
                              void* d_out, int out_size, void* d_ws, size_t ws_size,
                              hipStream_t stream) {
  const float* audio = (const float*)d_in[0];
  const float* Wmask = (const float*)d_in[1];
  float* out = (float*)d_out;

  // layout: [stats4 131136 | maxsq 64] (zeroed) | X 39,340,800 | Wc 39,340,800 |
  //         accum 39,518,208 | alpha 131,136 | Ksum 32,784
  char* ws = (char*)d_ws;
  const size_t off_stats4 = 0;
  const size_t off_maxsq  = 131136;
  const size_t zero_span  = 131200;
  const size_t off_X      = zero_span;
  const size_t off_Wc     = off_X + 39340800;
  const size_t off_accum  = off_Wc + 39340800;
  const size_t off_alpha  = off_accum + 39518208;
  const size_t off_Ksum   = off_alpha + 131136;

  float*        stats4f = (float*)(ws + off_stats4);
  float4*       stats4  = (float4*)(ws + off_stats4);
  unsigned int* maxsq   = (unsigned int*)(ws + off_maxsq);
  float2*       X       = (float2*)(ws + off_X);
  float2*       Wc      = (float2*)(ws + off_Wc);
  float*        accum   = (float*)(ws + off_accum);
  float*        alpha   = (float*)(ws + off_alpha);
  float*        Ksum    = (float*)(ws + off_Ksum);

  hipMemsetAsync(ws, 0, zero_span, stream);

  stft_kernel<<<2400, 256, 0, stream>>>(audio, X);
  stats_kernel<<<dim3(9, 4, 4), 256, 0, stream>>>(X, stats4f, maxsq);
  alpha_kernel<<<(4 * NB + 255) / 256, 256, 0, stream>>>(Wmask, stats4, maxsq, alpha, Ksum);
  wiener_kernel<<<(4 * 300 * NB + 255) / 256, 256, 0, stream>>>(X, stats4, Ksum, maxsq, Wc);
  istft_pass_kernel<0><<<2400, 256, 0, stream>>>(Wc, alpha, accum, out, 0);
  istft_pass_kernel<1><<<2400, 256, 0, stream>>>(Wc, alpha, accum, out, 1);
  istft_pass_kernel<1><<<2400, 256, 0, stream>>>(Wc, alpha, accum, out, 2);
  istft_pass_kernel<2><<<2400, 256, 0, stream>>>(Wc, alpha, accum, out, 3);
}

// Round 7
// 199.791 us; speedup vs baseline: 1.2100x; 1.2100x over previous
//
#include <hip/hip_runtime.h>
#include <math.h>

#define TLEN 613376
#define OLEN 617472          // 4096 + 1024*599
#define NFR  600             // total frames
#define NB   2049            // bins
#define PI_F  3.14159265358979323846f
#define PI2_F 6.28318530717958647693f
#define PHYS(i) ((i) + ((i) >> 4))   // LDS pad

// periodic hann window
__device__ __forceinline__ float winf(int j) {
  return 0.5f - 0.5f * __cosf(1.5339807878856412e-3f * (float)j);  // 2*pi/4096
}

__device__ __forceinline__ float wsum_at(int m) {   // OLA window-power sum (edge-aware)
  int f_max = m >> 10; if (f_max > 599) f_max = 599;
  int f_min = (m - 3072) >> 10; if (f_min < 0) f_min = 0;
  float ws = 0.f;
  for (int f2 = f_min; f2 <= f_max; ++f2) {
    float w = winf(m - (f2 << 10));
    ws += w * w;
  }
  return (ws > 1e-11f) ? ws : 1.0f;
}

__device__ __forceinline__ float reflect_load(const float* __restrict__ x, int pos) {
  int k = pos - 2048;
  if (k < 0) k = -k;
  else if (k >= TLEN) k = 2 * TLEN - 2 - k;
  return x[k];
}

__device__ __forceinline__ float2 cmul(float2 a, float2 b) {
  return make_float2(a.x * b.x - a.y * b.y, a.x * b.y + a.y * b.x);
}
__device__ __forceinline__ float2 cadd(float2 a, float2 b) { return make_float2(a.x + b.x, a.y + b.y); }
__device__ __forceinline__ float2 csub(float2 a, float2 b) { return make_float2(a.x - b.x, a.y - b.y); }
template<int SGN>
__device__ __forceinline__ float2 muli(float2 a) {   // multiply by SGN*i
  return (SGN > 0) ? make_float2(-a.y, a.x) : make_float2(a.y, -a.x);
}

template<int SGN>
__device__ __forceinline__ void fft4(float2 v[4]) {
  float2 t0 = cadd(v[0], v[2]), t1 = csub(v[0], v[2]);
  float2 t2 = cadd(v[1], v[3]), t3 = csub(v[1], v[3]);
  float2 it3 = muli<SGN>(t3);
  v[0] = cadd(t0, t2); v[2] = csub(t0, t2);
  v[1] = cadd(t1, it3); v[3] = csub(t1, it3);
}

template<int SGN>
__device__ __forceinline__ void fft8(float2 v[8]) {
  const float C = 0.70710678118654752440f;
  const float s = (SGN > 0) ? 1.0f : -1.0f;
  float2 t0 = cadd(v[0], v[4]), t1 = csub(v[0], v[4]);
  float2 t2 = cadd(v[2], v[6]), t3 = csub(v[2], v[6]);
  float2 e0 = cadd(t0, t2), e2 = csub(t0, t2);
  float2 it3 = muli<SGN>(t3);
  float2 e1 = cadd(t1, it3), e3 = csub(t1, it3);
  t0 = cadd(v[1], v[5]); t1 = csub(v[1], v[5]);
  t2 = cadd(v[3], v[7]); t3 = csub(v[3], v[7]);
  float2 o0 = cadd(t0, t2), o2 = csub(t0, t2);
  it3 = muli<SGN>(t3);
  float2 o1 = cadd(t1, it3), o3 = csub(t1, it3);
  float2 o1w = make_float2(C * (o1.x - s * o1.y), C * (o1.y + s * o1.x));
  float2 o2w = muli<SGN>(o2);
  float2 o3w = make_float2(C * (-o3.x - s * o3.y), C * (-o3.y + s * o3.x));
  v[0] = cadd(e0, o0);  v[4] = csub(e0, o0);
  v[1] = cadd(e1, o1w); v[5] = csub(e1, o1w);
  v[2] = cadd(e2, o2w); v[6] = csub(e2, o2w);
  v[3] = cadd(e3, o3w); v[7] = csub(e3, o3w);
}

template<int SGN>
__device__ __forceinline__ void twiddle8(float2 v[8], float ang) {
  float sn, cs;
  __sincosf((SGN > 0) ? ang : -ang, &sn, &cs);
  float2 w1 = make_float2(cs, sn);
  float2 w = w1;
  v[1] = cmul(v[1], w);
#pragma unroll
  for (int r = 2; r < 8; ++r) { w = cmul(w, w1); v[r] = cmul(v[r], w); }
}

// Stockham stages 1-3 (radix-8); stage-3 result left in LDS.
template<int SGN>
__device__ __forceinline__ void fft2048_mid(float2* lds, float2 v[8], int tid) {
  fft8<SGN>(v);
#pragma unroll
  for (int r = 0; r < 8; ++r) { int i = tid * 8 + r; lds[PHYS(i)] = v[r]; }
  __syncthreads();
#pragma unroll
  for (int r = 0; r < 8; ++r) v[r] = lds[PHYS(tid + 256 * r)];
  twiddle8<SGN>(v, PI2_F * (1.0f / 64.0f) * (float)(tid & 7));      // Ns=8
  fft8<SGN>(v);
  __syncthreads();
#pragma unroll
  for (int r = 0; r < 8; ++r) { int i = ((tid >> 3) << 6) + (tid & 7) + 8 * r; lds[PHYS(i)] = v[r]; }
  __syncthreads();
#pragma unroll
  for (int r = 0; r < 8; ++r) v[r] = lds[PHYS(tid + 256 * r)];
  twiddle8<SGN>(v, PI2_F * (1.0f / 512.0f) * (float)(tid & 63));    // Ns=64
  fft8<SGN>(v);
  __syncthreads();
#pragma unroll
  for (int r = 0; r < 8; ++r) { int i = ((tid >> 6) << 9) + (tid & 63) + 64 * r; lds[PHYS(i)] = v[r]; }
  __syncthreads();
}

// final radix-4 stage (Ns=512): butterfly jj in [0,512); outputs z[jj + 512 k] = u[k]
template<int SGN>
__device__ __forceinline__ void fft2048_last(const float2* lds, int jj, float2 u[4]) {
#pragma unroll
  for (int r = 0; r < 4; ++r) u[r] = lds[PHYS(jj + 512 * r)];
  float sn, cs;
  float ang = PI2_F * (1.0f / 2048.0f) * (float)jj;
  __sincosf((SGN > 0) ? ang : -ang, &sn, &cs);
  float2 w1 = make_float2(cs, sn);
  float2 w2 = cmul(w1, w1);
  float2 w3 = cmul(w2, w1);
  u[1] = cmul(u[1], w1); u[2] = cmul(u[2], w2); u[3] = cmul(u[3], w3);
  fft4<SGN>(u);
}

// ---------------- forward STFT: one block per (n,c,f) frame ----------------
__global__ __launch_bounds__(256, 6) void stft_kernel(const float* __restrict__ audio,
                                                      float2* __restrict__ X) {
  __shared__ float2 lds[2176];
  int bid = blockIdx.x;             // nc*600 + f
  int f  = bid % NFR;
  int nc = bid / NFR;
  const float* x = audio + (size_t)nc * TLEN;
  int tid = threadIdx.x;
  int base = f * 1024;
  float2 v[8];
#pragma unroll
  for (int r = 0; r < 8; ++r) {
    int k = tid + 256 * r;
    int j0 = 2 * k;
    v[r] = make_float2(reflect_load(x, base + j0)     * winf(j0),
                       reflect_load(x, base + j0 + 1) * winf(j0 + 1));
  }
  fft2048_mid<-1>(lds, v, tid);
  fft2048_last<-1>(lds, tid,        v);
  fft2048_last<-1>(lds, tid + 256,  v + 4);
  __syncthreads();
#pragma unroll
  for (int r = 0; r < 4; ++r) lds[PHYS(tid + 512 * r)] = v[r];
#pragma unroll
  for (int r = 0; r < 4; ++r) lds[PHYS(tid + 256 + 512 * r)] = v[4 + r];
  __syncthreads();
  float2* out = X + (size_t)bid * NB;
  float sn0, cs0;
  __sincosf(-PI_F * (float)tid * (1.0f / 2048.0f), &sn0, &cs0);
  float2 ph = make_float2(cs0, sn0);
  const float2 rot = make_float2(0.92387953251128675613f, -0.38268343236508977173f);
#pragma unroll
  for (int r = 0; r < 9; ++r) {
    int k = tid + 256 * r;
    if (k <= 2048) {
      float2 Zk = lds[PHYS(k & 2047)];
      float2 Zm = lds[PHYS((2048 - k) & 2047)];
      float Ex = 0.5f * (Zk.x + Zm.x), Ey = 0.5f * (Zk.y - Zm.y);
      float Dx = 0.5f * (Zk.x - Zm.x), Dy = 0.5f * (Zk.y + Zm.y);
      float Ox = Dy, Oy = -Dx;                       // O = -i*D
      out[k] = make_float2(Ex + Ox * ph.x - Oy * ph.y, Ey + Ox * ph.y + Oy * ph.x);
    }
    ph = cmul(ph, rot);
  }
}

// ------- per-(n,chunk,b) covariance stats (float4/bin) + fused chunk max -------
__global__ __launch_bounds__(256) void stats_kernel(const float2* __restrict__ X,
                                                    float* __restrict__ stats4,
                                                    unsigned int* __restrict__ maxsq) {
  __shared__ unsigned int sm;
  if (threadIdx.x == 0) sm = 0u;
  __syncthreads();
  int b = blockIdx.x * 256 + threadIdx.x;
  bool ok = (b < NB);
  int g = blockIdx.y;                 // n*2 + chunk
  int n = g >> 1, chunk = g & 1;
  int t0 = blockIdx.z * 75;
  const float2* X0 = X + ((size_t)(n * 2 + 0) * NFR + chunk * 300 + t0) * NB + (ok ? b : 0);
  const float2* X1 = X + ((size_t)(n * 2 + 1) * NFR + chunk * 300 + t0) * NB + (ok ? b : 0);
  float s00 = 0.f, s11 = 0.f, sre = 0.f, sim = 0.f, lmax = 0.f;
  if (ok) {
    for (int t = 0; t < 75; ++t) {
      float2 a = X0[(size_t)t * NB];
      float2 c = X1[(size_t)t * NB];
      float pa = a.x * a.x + a.y * a.y;
      float pc = c.x * c.x + c.y * c.y;
      s00 += pa; s11 += pc;
      sre += a.x * c.x + a.y * c.y;
      sim += a.y * c.x - a.x * c.y;
      lmax = fmaxf(lmax, fmaxf(pa, pc));
    }
  }
  atomicMax(&sm, __float_as_uint(lmax));
  __syncthreads();
  if (threadIdx.x == 0) atomicMax(&maxsq[g], sm);
  if (ok) {
    float* sp = stats4 + ((size_t)g * NB + b) * 4;
    unsafeAtomicAdd(sp + 0, s00);
    unsafeAtomicAdd(sp + 1, s11);
    unsafeAtomicAdd(sp + 2, sre);
    unsafeAtomicAdd(sp + 3, sim);
  }
}

// ---------------- alpha_s + K = sum_s alpha per (g,b) ----------------
__global__ __launch_bounds__(256) void alpha_kernel(const float* __restrict__ Wmask,
                                                    const float4* __restrict__ stats4,
                                                    const unsigned int* __restrict__ maxsq,
                                                    float* __restrict__ alpha,
                                                    float* __restrict__ Ksum) {
  int idx = blockIdx.x * 256 + threadIdx.x;
  if (idx >= 4 * NB) return;
  int b = idx % NB;
  int g = idx / NB;
  float ma2 = fmaxf(1.0f, __uint_as_float(maxsq[g]) * 0.01f);   // max_abs^2
  float4 s4 = stats4[(size_t)g * NB + b];
  float P = 0.5f * (s4.x + s4.y) / ma2;
  float K = 0.f;
#pragma unroll
  for (int s = 0; s < 4; ++s) {
    float mv = 1.0f / (1.0f + expf(-Wmask[s * NB + b]));
    float m2 = mv * mv;
    float a = (m2 * m2) / (1e-10f + m2 * P);
    alpha[(size_t)(g * 4 + s) * NB + b] = a;
    K += a;
  }
  Ksum[(size_t)g * NB + b] = K;
}

// ------- Wiener core (s-independent field): Wc[t,c] = p̂ * (G * inv(Cxx) * x)[c] -------
__global__ __launch_bounds__(256) void wiener_kernel(const float2* __restrict__ X,
                                                     const float4* __restrict__ stats4,
                                                     const float* __restrict__ Ksum,
                                                     const unsigned int* __restrict__ maxsq,
                                                     float2* __restrict__ Wc) {
  int idx = blockIdx.x * 256 + threadIdx.x;
  if (idx >= 4 * 300 * NB) return;
  int b = idx % NB;
  int gt = idx / NB;
  int t = gt % 300;
  int g = gt / 300;
  int n = g >> 1, chunk = g & 1;
  int f = chunk * 300 + t;
  float ima2 = 1.0f / fmaxf(1.0f, __uint_as_float(maxsq[g]) * 0.01f);
  float4 s4 = stats4[(size_t)g * NB + b];
  float g00 = s4.x * ima2, g11 = s4.y * ima2, gre = s4.z * ima2, gim = s4.w * ima2;
  float K = Ksum[(size_t)g * NB + b];
  float2 x0 = X[((size_t)(n * 2 + 0) * NFR + f) * NB + b];
  float2 x1 = X[((size_t)(n * 2 + 1) * NFR + f) * NB + b];
  float ph = 0.5f * ((x0.x * x0.x + x0.y * x0.y) + (x1.x * x1.x + x1.y * x1.y)) * ima2;
  float pk = ph * K;
  float M00 = 1e-5f + pk * g00;
  float M11 = 1e-5f + pk * g11;
  float Mre = pk * gre, Mim = pk * gim;                // M01
  float det = M00 * M11 - (Mre * Mre + Mim * Mim);
  float sc = ph / det;
  float u0x = M11 * x0.x - (Mre * x1.x - Mim * x1.y);
  float u0y = M11 * x0.y - (Mre * x1.y + Mim * x1.x);
  float u1x = M00 * x1.x - (Mre * x0.x + Mim * x0.y);
  float u1y = M00 * x1.y - (Mre * x0.y - Mim * x0.x);
  float w0x = g00 * u0x + (gre * u1x - gim * u1y);
  float w0y = g00 * u0y + (gre * u1y + gim * u1x);
  float w1x = (gre * u0x + gim * u0y) + g11 * u1x;
  float w1y = (gre * u0y - gim * u0x) + g11 * u1y;
  float2* out = Wc + ((size_t)(n * NFR + f) * 2) * NB + b;
  out[0]  = make_float2(w0x * sc, w0y * sc);
  out[NB] = make_float2(w1x * sc, w1y * sc);
}

// ---- inverse rFFT per frame + NON-ATOMIC OLA; MODE: 0=store, 1=add, 2=add+finalize ----
template<int MODE>
__global__ __launch_bounds__(256, 6) void istft_pass_kernel(const float2* __restrict__ Wc,
                                                            const float* __restrict__ alpha,
                                                            float* __restrict__ accum,
                                                            float* __restrict__ out,
                                                            int pass) {
  __shared__ float2 lds[2176];
  int bid = blockIdx.x;                  // plane*150 + fi, plane = ((n*4+s)*2+c)
  int fi = bid % 150;
  int plane = bid / 150;
  int c = plane & 1;
  int s = (plane >> 1) & 3;
  int n = plane >> 3;
  int f = 4 * fi + pass;
  int g = n * 2 + (f >= 300 ? 1 : 0);
  int tid = threadIdx.x;
  const float2* Wrow = Wc + ((size_t)(n * NFR + f) * 2 + c) * NB;
  const float*  arow = alpha + (size_t)(g * 4 + s) * NB;
  float* acc = accum + (size_t)plane * OLEN + (size_t)f * 1024;

  // Prefetch the OLA read-modify-write inputs before the FFT (addresses known
  // at entry) so the global read latency hides behind the FFT compute.
  // NOTE: needs the 6-wave launch bound; an 8-wave bound caps VGPRs at 64 and
  // forces scratch spills (round-6 regression).
  float2 pre[8];
  if (MODE >= 1) {
#pragma unroll
    for (int half = 0; half < 2; ++half) {
#pragma unroll
      for (int r = 0; r < 4; ++r) {
        int m = tid + 256 * half + 512 * r;
        pre[half * 4 + r] = *(const float2*)&acc[2 * m];
      }
    }
  }

  float2 v[8];
  float sn0, cs0;
  __sincosf(PI_F * (float)tid * (1.0f / 2048.0f), &sn0, &cs0);
  float2 ph = make_float2(cs0, sn0);
  const float2 rot = make_float2(0.92387953251128675613f, 0.38268343236508977173f);
#pragma unroll
  for (int r = 0; r < 8; ++r) {
    int k = tid + 256 * r;
    float ak = arow[k];
    float2 sk = Wrow[k]; sk.x *= ak; sk.y *= ak;
    int rk = 2048 - k;
    float am = arow[rk];
    float2 sv = Wrow[rk]; sv.x *= am; sv.y *= am;
    float Ex = 0.5f * (sk.x + sv.x), Ey = 0.5f * (sk.y - sv.y);
    float Dx = 0.5f * (sk.x - sv.x), Dy = 0.5f * (sk.y + sv.y);
    float Ox = Dx * ph.x - Dy * ph.y, Oy = Dx * ph.y + Dy * ph.x;  // O = D*e^{+i pi k/2048}
    v[r] = make_float2(Ex - Oy, Ey + Ox);                           // Z = E + iO
    ph = cmul(ph, rot);
  }
  fft2048_mid<1>(lds, v, tid);
  float* outp = out + (size_t)plane * TLEN;
  const float scale = 1.0f / 2048.0f;
#pragma unroll
  for (int half = 0; half < 2; ++half) {
    int jj = tid + 256 * half;
    float2 u[4];
    fft2048_last<1>(lds, jj, u);
#pragma unroll
    for (int r = 0; r < 4; ++r) {
      int m = jj + 512 * r;
      int j0 = 2 * m;
      float2 val = make_float2(u[r].x * scale * winf(j0),
                               u[r].y * scale * winf(j0 + 1));
      float2* p = (float2*)&acc[j0];
      if (MODE == 0) {
        *p = val;
      } else if (MODE == 1) {
        float2 o = pre[half * 4 + r];
        val.x += o.x; val.y += o.y;
        *p = val;
      } else {
        int gm = f * 1024 + j0;                       // accum coordinate (even)
        if (gm < 615424) {                            // out covers [2048, 615424)
          float2 o = pre[half * 4 + r];
          val.x += o.x; val.y += o.y;
          float i0, i1;
          if (gm >= 3072 && gm + 1 < 614400) {        // interior: wsum == 1.5
            i0 = 0.66666666666666667f; i1 = i0;
          } else {
            i0 = 1.0f / wsum_at(gm); i1 = 1.0f / wsum_at(gm + 1);
          }
          float2* po = (float2*)&outp[gm - 2048];
          *po = make_float2(val.x * i0, val.y * i1);
        }
      }
    }
  }
  if (MODE == 0 && fi == 149) {
    // zero the plane tail [614400, OLEN) not covered by class-0 frames
    float* tail = accum + (size_t)plane * OLEN + 614400;
    for (int i = tid; i < OLEN - 614400; i += 256) tail[i] = 0.f;
  }
  if (MODE == 2 && fi == 0) {
    // finalize head samples m in [2048, 3072): complete after pass 2
    float* accp = accum + (size_t)plane * OLEN;
    for (int m = 2048 + tid; m < 3072; m += 256) {
      outp[m - 2048] = accp[m] / wsum_at(m);
    }
  }
}

extern "C" void kernel_launch(void* const* d_in, const int* in_sizes, int n_in,
                              void* d_out, int out_size, void* d_ws, size_t ws_size,
                              hipStream_t stream) {
  const float* audio = (const float*)d_in[0];
  const float* Wmask = (const float*)d_in[1];
  float* out = (float*)d_out;

  // layout: [stats4 131136 | maxsq 64] (zeroed) | X 39,340,800 | Wc 39,340,800 |
  //         accum 39,518,208 | alpha 131,136 | Ksum 32,784
  char* ws = (char*)d_ws;
  const size_t off_stats4 = 0;
  const size_t off_maxsq  = 131136;
  const size_t zero_span  = 131200;
  const size_t off_X      = zero_span;
  const size_t off_Wc     = off_X + 39340800;
  const size_t off_accum  = off_Wc + 39340800;
  const size_t off_alpha  = off_accum + 39518208;
  const size_t off_Ksum   = off_alpha + 131136;

  float*        stats4f = (float*)(ws + off_stats4);
  float4*       stats4  = (float4*)(ws + off_stats4);
  unsigned int* maxsq   = (unsigned int*)(ws + off_maxsq);
  float2*       X       = (float2*)(ws + off_X);
  float2*       Wc      = (float2*)(ws + off_Wc);
  float*        accum   = (float*)(ws + off_accum);
  float*        alpha   = (float*)(ws + off_alpha);
  float*        Ksum    = (float*)(ws + off_Ksum);

  hipMemsetAsync(ws, 0, zero_span, stream);

  stft_kernel<<<2400, 256, 0, stream>>>(audio, X);
  stats_kernel<<<dim3(9, 4, 4), 256, 0, stream>>>(X, stats4f, maxsq);
  alpha_kernel<<<(4 * NB + 255) / 256, 256, 0, stream>>>(Wmask, stats4, maxsq, alpha, Ksum);
  wiener_kernel<<<(4 * 300 * NB + 255) / 256, 256, 0, stream>>>(X, stats4, Ksum, maxsq, Wc);
  istft_pass_kernel<0><<<2400, 256, 0, stream>>>(Wc, alpha, accum, out, 0);
  istft_pass_kernel<1><<<2400, 256, 0, stream>>>(Wc, alpha, accum, out, 1);
  istft_pass_kernel<1><<<2400, 256, 0, stream>>>(Wc, alpha, accum, out, 2);
  istft_pass_kernel<2><<<2400, 256, 0, stream>>>(Wc, alpha, accum, out, 3);
}